// Round 9
// baseline (439.234 us; speedup 1.0000x reference)
//
#include <hip/hip_runtime.h>
#include <hip/hip_bf16.h>
#include <stdint.h>

typedef __attribute__((ext_vector_type(8))) short short8;
typedef __attribute__((ext_vector_type(4))) float f32x4;
typedef __attribute__((ext_vector_type(16))) float f32x16;

constexpr int kDim   = 1536;
constexpr int kHeads = 12;
constexpr int kHd    = 128;
constexpr int kS     = 3072;
constexpr int kB     = 2;
constexpr int kQKV   = 3 * kDim;               // 4608 fused row width
constexpr float kEps   = 1e-6f;
constexpr float kQMul  = 0.08838834764831845f * 1.44269504089f; // 1/sqrt(128)*log2(e)

__device__ __forceinline__ ushort f2bf(float f) {
    union { float f; uint32_t u; } c; c.f = f;
    uint32_t u = c.u;
    return (ushort)((u + 0x7fffu + ((u >> 16) & 1u)) >> 16);
}
__device__ __forceinline__ float bf2f(uint32_t h) {
    union { uint32_t u; float f; } c; c.u = h << 16;
    return c.f;
}
__device__ __forceinline__ void gload_lds16(const void* g, void* l) {
    __builtin_amdgcn_global_load_lds((const __attribute__((address_space(1))) void*)g,
                                     (__attribute__((address_space(3))) void*)l, 16, 0, 0);
}
__device__ __forceinline__ uint32_t cvtpk_bf16(float lo, float hi) {
    uint32_t r;
    asm("v_cvt_pk_bf16_f32 %0, %1, %2" : "=v"(r) : "v"(lo), "v"(hi));
    return r;
}

// ---------------------------------------------------------------------------
// fp32 -> bf16 convert, 8 elems/thread
// ---------------------------------------------------------------------------
__global__ __launch_bounds__(256)
void cvt_kernel(const float* __restrict__ in, ushort* __restrict__ out, int n8)
{
    int i = blockIdx.x * 256 + threadIdx.x;
    if (i >= n8) return;
    const float4* p = (const float4*)in + (size_t)i * 2;
    float4 a = p[0], b = p[1];
    uint4 r;
    r.x = (uint32_t)f2bf(a.x) | ((uint32_t)f2bf(a.y) << 16);
    r.y = (uint32_t)f2bf(a.z) | ((uint32_t)f2bf(a.w) << 16);
    r.z = (uint32_t)f2bf(b.x) | ((uint32_t)f2bf(b.y) << 16);
    r.w = (uint32_t)f2bf(b.z) | ((uint32_t)f2bf(b.w) << 16);
    ((uint4*)out)[i] = r;
}

// 4 weight tensors in one dispatch (blockIdx.y selects)
__global__ __launch_bounds__(256)
void cvt4_kernel(const float* __restrict__ s0, const float* __restrict__ s1,
                 const float* __restrict__ s2, const float* __restrict__ s3,
                 ushort* __restrict__ d0, ushort* __restrict__ d1,
                 ushort* __restrict__ d2, ushort* __restrict__ d3, int n8)
{
    int i = blockIdx.x * 256 + threadIdx.x;
    if (i >= n8) return;
    const float* in; ushort* out;
    switch (blockIdx.y) {
        case 0: in = s0; out = d0; break;
        case 1: in = s1; out = d1; break;
        case 2: in = s2; out = d2; break;
        default: in = s3; out = d3; break;
    }
    const float4* p = (const float4*)in + (size_t)i * 2;
    float4 a = p[0], b = p[1];
    uint4 r;
    r.x = (uint32_t)f2bf(a.x) | ((uint32_t)f2bf(a.y) << 16);
    r.y = (uint32_t)f2bf(a.z) | ((uint32_t)f2bf(a.w) << 16);
    r.z = (uint32_t)f2bf(b.x) | ((uint32_t)f2bf(b.y) << 16);
    r.w = (uint32_t)f2bf(b.z) | ((uint32_t)f2bf(b.w) << 16);
    ((uint4*)out)[i] = r;
}

// concat bq|bk|bv -> biasqkv[4608]
__global__ __launch_bounds__(256)
void biascat_kernel(const float* __restrict__ bq, const float* __restrict__ bk,
                    const float* __restrict__ bv, float* __restrict__ out)
{
    int i = blockIdx.x * 256 + threadIdx.x;
    if (i >= kQKV) return;
    float v = (i < kDim) ? bq[i] : (i < 2*kDim) ? bk[i - kDim] : bv[i - 2*kDim];
    out[i] = v;
}

// ---------------------------------------------------------------------------
// bf16 MFMA GEMM: C[M][N] = A[M][K] @ B[N][K]^T + bias.  128^2 tile, BK=32,
// 2-deep counted prefetch: per iter {compute j; sync (drains tile j+1 loads,
// issued one full compute phase earlier); stage tile j+2 into buf[j&1]}.
// Ledger: buf[j&1] is rewritten only after the barrier where every wave
// finished reading it; the barrier's implicit vmcnt(0) guarantees tile j+1
// landed before iter j+1 reads it.
// ---------------------------------------------------------------------------
template<typename OutT>
__global__ __launch_bounds__(256)
void gemm_bf16(const ushort* __restrict__ A, const ushort* __restrict__ B,
               const float* __restrict__ bias, OutT* __restrict__ C,
               int M, int N, int K)
{
    __shared__ ushort As[2][128 * 32];
    __shared__ ushort Bs[2][128 * 32];
    const int t    = threadIdx.x;
    const int lane = t & 63;
    const int w    = t >> 6;
    const int wm = (w >> 1) * 64, wn = (w & 1) * 64;
    const int m0 = blockIdx.y * 128, n0 = blockIdx.x * 128;

    const int srow = t >> 2;
    const int skc  = (t & 3) * 8;
    const ushort* Ag = A + (size_t)(m0 + srow) * K + skc;
    const ushort* Bg = B + (size_t)(n0 + srow) * K + skc;
    const size_t half = (size_t)64 * K;
    const int Nk = K / 32;

    f32x4 acc[4][4];
    #pragma unroll
    for (int m = 0; m < 4; ++m)
        #pragma unroll
        for (int n = 0; n < 4; ++n)
            #pragma unroll
            for (int i = 0; i < 4; ++i) acc[m][n][i] = 0.f;

    const int kk  = (lane >> 4) * 8;
    const int l15 = lane & 15;

    // prologue: stage tiles 0 and 1
    {
        gload_lds16(Ag,            &As[0][t * 8]);
        gload_lds16(Ag + half,     &As[0][t * 8 + 2048]);
        gload_lds16(Bg,            &Bs[0][t * 8]);
        gload_lds16(Bg + half,     &Bs[0][t * 8 + 2048]);
        gload_lds16(Ag + 32,        &As[1][t * 8]);
        gload_lds16(Ag + half + 32, &As[1][t * 8 + 2048]);
        gload_lds16(Bg + 32,        &Bs[1][t * 8]);
        gload_lds16(Bg + half + 32, &Bs[1][t * 8 + 2048]);
    }
    __syncthreads();

    for (int j = 0; j < Nk; ++j) {
        const int cur = j & 1;
        short8 af[4], bf[4];
        #pragma unroll
        for (int m = 0; m < 4; ++m) af[m] = *(const short8*)&As[cur][(wm + m*16 + l15) * 32 + kk];
        #pragma unroll
        for (int n = 0; n < 4; ++n) bf[n] = *(const short8*)&Bs[cur][(wn + n*16 + l15) * 32 + kk];
        #pragma unroll
        for (int m = 0; m < 4; ++m)
            #pragma unroll
            for (int n = 0; n < 4; ++n)
                acc[m][n] = __builtin_amdgcn_mfma_f32_16x16x32_bf16(af[m], bf[n], acc[m][n], 0, 0, 0);

        __syncthreads();   // drains tile j+1 loads (issued >= 1 phase ago) + frees buf[cur]
        if (j + 2 < Nk) {
            const int k2 = (j + 2) * 32;
            gload_lds16(Ag + k2,        &As[cur][t * 8]);
            gload_lds16(Ag + half + k2, &As[cur][t * 8 + 2048]);
            gload_lds16(Bg + k2,        &Bs[cur][t * 8]);
            gload_lds16(Bg + half + k2, &Bs[cur][t * 8 + 2048]);
        }
    }

    const int r0 = (lane >> 4) * 4;
    #pragma unroll
    for (int m = 0; m < 4; ++m) {
        #pragma unroll
        for (int r = 0; r < 4; ++r) {
            const size_t row = (size_t)(m0 + wm + m*16 + r0 + r);
            #pragma unroll
            for (int n = 0; n < 4; ++n) {
                const int col = n0 + wn + n*16 + l15;
                float val = acc[m][n][r] + bias[col];
                if constexpr (sizeof(OutT) == 4) C[row * N + col] = val;
                else                             C[row * N + col] = f2bf(val);
            }
        }
    }
}

// ---------------------------------------------------------------------------
// V transpose from fused qkv: vt[b][h][d][s] = qkv[b][s][3072 + h*128 + d]
// ---------------------------------------------------------------------------
__global__ __launch_bounds__(256)
void vtrans_kernel(const ushort* __restrict__ qkv, ushort* __restrict__ vt)
{
    __shared__ ushort Ts[64][72];
    const int t  = threadIdx.x;
    const int s0 = blockIdx.x * 64;
    const int d0 = blockIdx.y * 64;
    const int bh = blockIdx.z;
    const int b = bh / kHeads, h = bh % kHeads;

    const int r = t >> 2, cc = (t & 3) * 16;
    const ushort* src = qkv + ((size_t)(b * kS) + s0 + r) * kQKV + 2*kDim + h * kHd + d0 + cc;
    uint4 a0 = *(const uint4*)src;
    uint4 a1 = *(const uint4*)(src + 8);
    *(uint4*)&Ts[r][cc]     = a0;
    *(uint4*)&Ts[r][cc + 8] = a1;
    __syncthreads();
    ushort tmp[16];
    #pragma unroll
    for (int j = 0; j < 16; ++j) tmp[j] = Ts[cc + j][r];
    ushort* dst = vt + ((size_t)(bh * kHd) + d0 + r) * kS + s0 + cc;
    *(uint4*)dst       = *(uint4*)&tmp[0];
    *(uint4*)(dst + 8) = *(uint4*)&tmp[8];
}

// ---------------------------------------------------------------------------
// RMSNorm + RoPE on q/k sections of fused qkv. 192 thr, 8 elems each.
// ---------------------------------------------------------------------------
__global__ __launch_bounds__(192)
void rmsrope_kernel(ushort* __restrict__ qkv,
                    const float* __restrict__ gq, const float* __restrict__ gk,
                    const float* __restrict__ freqs, const int* __restrict__ grid_sizes)
{
    __shared__ float red[4];
    const int row   = blockIdx.x;
    const int which = blockIdx.y;
    ushort* ptr = qkv + (size_t)row * kQKV + which * kDim;
    const float* g = which ? gk : gq;
    const float outmul = which ? 1.0f : kQMul;
    const int t = threadIdx.x;

    uint4 raw = ((const uint4*)ptr)[t];
    float v[8];
    v[0] = bf2f(raw.x & 0xffff); v[1] = bf2f(raw.x >> 16);
    v[2] = bf2f(raw.y & 0xffff); v[3] = bf2f(raw.y >> 16);
    v[4] = bf2f(raw.z & 0xffff); v[5] = bf2f(raw.z >> 16);
    v[6] = bf2f(raw.w & 0xffff); v[7] = bf2f(raw.w >> 16);

    float ss = 0.f;
    #pragma unroll
    for (int i = 0; i < 8; ++i) ss += v[i] * v[i];
    #pragma unroll
    for (int off = 32; off >= 1; off >>= 1) ss += __shfl_xor(ss, off);
    if ((t & 63) == 0) red[t >> 6] = ss;
    __syncthreads();
    const float scale = rsqrtf((red[0] + red[1] + red[2]) * (1.f / kDim) + kEps);

    const int b = row / kS, s = row % kS;
    const int gh = grid_sizes[b*3 + 1], gw = grid_sizes[b*3 + 2];
    const int hw  = gh * gw;
    const int fi  = s / hw;
    const int rem = s - fi * hw;
    const int hi  = rem / gw;
    const int wi  = rem - hi * gw;

    const float4 g0 = *(const float4*)(g + t*8);
    const float4 g1 = *(const float4*)(g + t*8 + 4);
    const float gv[8] = {g0.x, g0.y, g0.z, g0.w, g1.x, g1.y, g1.z, g1.w};

    uint32_t out[4];
    #pragma unroll
    for (int jj = 0; jj < 4; ++jj) {
        const int p = t*4 + jj;
        const int c = p & 63;
        const int pos = (c < 22) ? fi : (c < 43 ? hi : wi);
        const float ang = freqs[pos * 64 + c];
        float sn, cs;
        sincosf(ang, &sn, &cs);
        const float e0 = v[2*jj]   * scale * gv[2*jj];
        const float e1 = v[2*jj+1] * scale * gv[2*jj+1];
        const float o0 = (e0 * cs - e1 * sn) * outmul;
        const float o1 = (e0 * sn + e1 * cs) * outmul;
        out[jj] = (uint32_t)f2bf(o0) | ((uint32_t)f2bf(o1) << 16);
    }
    uint4 ov; ov.x = out[0]; ov.y = out[1]; ov.z = out[2]; ov.w = out[3];
    ((uint4*)ptr)[t] = ov;
}

// ---------------------------------------------------------------------------
// Flash attention, split-K (2 halves), swapped-QK^T 32x32x16 MFMA.
// 1D grid 1152, XCD-bijective remap; block -> (qtile, half, h, b).
// Writes normalized partial O' (bf16) + per-row (m,l) to workspace.
// launch_bounds (256,2): (256,4) forced VGPR<=64 -> 0.5 GB/dispatch spill.
// ---------------------------------------------------------------------------
__global__ __launch_bounds__(256, 2)
void attn_kernel(const ushort* __restrict__ qkv, const ushort* __restrict__ vtb,
                 ushort* __restrict__ pA, ushort* __restrict__ pB,
                 float* __restrict__ ml, const int* __restrict__ seq_lens)
{
    __shared__ ushort Ks[64 * 128];
    __shared__ ushort VT[128 * 64];

    // bijective XCD remap: consecutive logical ids (sharing (h,b) K/V) land on
    // the same XCD's L2.  1152 % 8 == 0 -> L = (lin&7)*144 + (lin>>3).
    const int lin = blockIdx.x;
    const int L   = (lin & 7) * 144 + (lin >> 3);
    const int bh   = L / 48;
    const int rem  = L - bh * 48;
    const int half = rem / 24;
    const int qtile= rem - half * 24;
    const int h = bh % kHeads, b = bh / kHeads;
    const int seq = seq_lens[b];
    const int kbeg = half * (kS / 2);

    const int t = threadIdx.x, lane = t & 63, w = t >> 6;
    const int l31 = lane & 31, hi = lane >> 5;
    const int qrow = qtile * 128 + w * 32 + l31;

    const ushort* qbase = qkv + ((size_t)b * kS) * kQKV + h * kHd;
    const ushort* kbase = qkv + ((size_t)b * kS) * kQKV + kDim + h * kHd;
    const ushort* vtbase = vtb + ((size_t)(b * kHeads + h) * kHd) * kS;

    // Q fragments (B-operand): qf[kb][j] = Q[qrow][kb*16 + hi*8 + j]
    short8 qf[8];
    #pragma unroll
    for (int kb = 0; kb < 8; ++kb)
        qf[kb] = *(const short8*)(qbase + (size_t)qrow * kQKV + kb*16 + hi*8);

    f32x16 oacc[4];
    #pragma unroll
    for (int n = 0; n < 4; ++n)
        #pragma unroll
        for (int i = 0; i < 16; ++i) oacc[n][i] = 0.f;

    float m_run = -1e30f, l_run = 0.f;

    const int srow = t >> 4;                      // 0..15
    const int scol = (t & 15) * 8;
    const int kl   = scol ^ ((srow & 7) << 3);    // pre-swizzled K source col
    const int vd0  = t >> 3;                      // 0..31
    const int vscol = ((t & 7) * 8) ^ ((vd0 & 7) << 3);  // pre-swizzled V^T col

    for (int kt = 0; kt < kS/2; kt += 64) {
        const int k0 = kbeg + kt;
        __syncthreads();
        #pragma unroll
        for (int c = 0; c < 4; ++c) {
            gload_lds16(kbase + (size_t)(k0 + srow + c*16) * kQKV + kl, &Ks[t*8 + c*2048]);
            gload_lds16(vtbase + (size_t)(vd0 + c*32) * kS + k0 + vscol, &VT[t*8 + c*2048]);
        }
        __syncthreads();

        // ---- S^T = K . Q^T : col(lane&31)=qrow, reg r -> key (r&3)+8*(r>>2)+4*hi
        f32x16 s0, s1;
        #pragma unroll
        for (int i = 0; i < 16; ++i) { s0[i] = 0.f; s1[i] = 0.f; }
        __builtin_amdgcn_s_setprio(1);
        #pragma unroll
        for (int kb = 0; kb < 8; ++kb) {
            const int col = (kb*16 + hi*8) ^ ((l31 & 7) << 3);
            short8 kf0 = *(const short8*)&Ks[l31 * 128 + col];
            short8 kf1 = *(const short8*)&Ks[(32 + l31) * 128 + col];
            s0 = __builtin_amdgcn_mfma_f32_32x32x16_bf16(kf0, qf[kb], s0, 0, 0, 0);
            s1 = __builtin_amdgcn_mfma_f32_32x32x16_bf16(kf1, qf[kb], s1, 0, 0, 0);
        }
        __builtin_amdgcn_s_setprio(0);

        // ---- mask + tile max (scores already in log2 domain via kQMul) ----
        float mx = -1e30f;
        if (k0 + 64 > seq) {
            #pragma unroll
            for (int r = 0; r < 16; ++r) {
                const int key = k0 + (r&3) + 8*(r>>2) + 4*hi;
                if (key >= seq)      s0[r] = -1e30f;
                if (key + 32 >= seq) s1[r] = -1e30f;
                mx = fmaxf(fmaxf(mx, s0[r]), s1[r]);
            }
        } else {
            #pragma unroll
            for (int r = 0; r < 16; ++r) mx = fmaxf(fmaxf(mx, s0[r]), s1[r]);
        }
        mx = fmaxf(mx, __shfl_xor(mx, 32));

        // ---- defer-max online softmax (T13) ----
        const bool skip = (mx <= m_run + 11.0f);
        if (!__all(skip)) {
            const float mnew = fmaxf(m_run, mx);
            const float alpha = exp2f(m_run - mnew);
            m_run = mnew;
            l_run *= alpha;
            #pragma unroll
            for (int r = 0; r < 16; ++r) {
                const float ar = __shfl(alpha, (r&3) + 8*(r>>2) + 4*hi);
                #pragma unroll
                for (int n = 0; n < 4; ++n) oacc[n][r] *= ar;
            }
        }

        float rs = 0.f;
        #pragma unroll
        for (int r = 0; r < 16; ++r) {
            s0[r] = exp2f(s0[r] - m_run);
            s1[r] = exp2f(s1[r] - m_run);
            rs += s0[r] + s1[r];
        }
        rs += __shfl_xor(rs, 32);
        l_run += rs;

        // ---- pack P -> bf16 dwords (cvt_pk), exchange halves (shfl_xor) ----
        uint32_t u0[8], u1[8], w0[8], w1[8];
        #pragma unroll
        for (int i = 0; i < 8; ++i) {
            u0[i] = cvtpk_bf16(s0[2*i], s0[2*i+1]);
            u1[i] = cvtpk_bf16(s1[2*i], s1[2*i+1]);
        }
        #pragma unroll
        for (int i = 0; i < 8; ++i) {
            w0[i] = __shfl_xor(u0[i], 32);
            w1[i] = __shfl_xor(u1[i], 32);
        }
        union PF { uint32_t d[4]; short8 s8; };
        PF pa[4];
        pa[0].d[0] = hi ? w0[2] : u0[0];  pa[0].d[1] = hi ? w0[3] : u0[1];
        pa[0].d[2] = hi ? u0[2] : w0[0];  pa[0].d[3] = hi ? u0[3] : w0[1];
        pa[1].d[0] = hi ? w0[6] : u0[4];  pa[1].d[1] = hi ? w0[7] : u0[5];
        pa[1].d[2] = hi ? u0[6] : w0[4];  pa[1].d[3] = hi ? u0[7] : w0[5];
        pa[2].d[0] = hi ? w1[2] : u1[0];  pa[2].d[1] = hi ? w1[3] : u1[1];
        pa[2].d[2] = hi ? u1[2] : w1[0];  pa[2].d[3] = hi ? u1[3] : w1[1];
        pa[3].d[0] = hi ? w1[6] : u1[4];  pa[3].d[1] = hi ? w1[7] : u1[5];
        pa[3].d[2] = hi ? u1[6] : w1[4];  pa[3].d[3] = hi ? u1[7] : w1[5];

        // ---- PV: oacc[n] over d-blocks, k-slots 0..3 ----
        __builtin_amdgcn_s_setprio(1);
        #pragma unroll
        for (int ks = 0; ks < 4; ++ks) {
            #pragma unroll
            for (int n = 0; n < 4; ++n) {
                const int d = n*32 + l31;
                const int colv = (ks*16 + hi*8) ^ ((l31 & 7) << 3);
                short8 vf = *(const short8*)&VT[d * 64 + colv];
                oacc[n] = __builtin_amdgcn_mfma_f32_32x32x16_bf16(pa[ks].s8, vf, oacc[n], 0, 0, 0);
            }
        }
        __builtin_amdgcn_s_setprio(0);
    }

    // ---- epilogue: partial O' = O~/l (bf16) + per-row (m,l) ----
    ushort* pOut = half ? pB : pA;
    const float linv = 1.f / l_run;
    #pragma unroll
    for (int r = 0; r < 16; ++r) {
        const int qr = (r&3) + 8*(r>>2) + 4*hi;
        const float lr = __shfl(linv, qr);
        const size_t row = (size_t)(b * kS) + qtile * 128 + w * 32 + qr;
        #pragma unroll
        for (int n = 0; n < 4; ++n)
            pOut[row * kDim + h * kHd + n*32 + l31] = f2bf(oacc[n][r] * lr);
    }
    if (lane < 32) {
        const int s = qtile * 128 + w * 32 + l31;
        const size_t idx = ((((size_t)(b * kHeads + h)) * 2 + half) * kS + s) * 2;
        ml[idx]     = m_run;
        ml[idx + 1] = l_run;
    }
}

// ---------------------------------------------------------------------------
// Combine split-K partials: O = (a0*O'0 + a1*O'1)/(a0+a1), a_i = l_i*2^(m_i-m)
// ---------------------------------------------------------------------------
__global__ __launch_bounds__(256)
void combine_kernel(const ushort* __restrict__ pA, const ushort* __restrict__ pB,
                    const float* __restrict__ ml, ushort* __restrict__ out, int n8)
{
    int i = blockIdx.x * 256 + threadIdx.x;
    if (i >= n8) return;
    const int row = i / 192;               // 192 = kDim/8
    const int within = (i - row * 192) * 8;
    const int h = within >> 7;
    const int b = row / kS;
    const int s = row - b * kS;
    const size_t base = (((size_t)(b * kHeads + h)) * 2) * kS;
    const float m0 = ml[(base + s) * 2],        l0 = ml[(base + s) * 2 + 1];
    const float m1 = ml[(base + kS + s) * 2],   l1 = ml[(base + kS + s) * 2 + 1];
    const float m  = fmaxf(m0, m1);
    const float a0 = l0 * exp2f(m0 - m);
    const float a1 = l1 * exp2f(m1 - m);
    const float inv = 1.f / (a0 + a1);
    const float f0 = a0 * inv, f1 = a1 * inv;

    uint4 ua = ((const uint4*)pA)[i];
    uint4 ub = ((const uint4*)pB)[i];
    const uint32_t* da = (const uint32_t*)&ua;
    const uint32_t* db = (const uint32_t*)&ub;
    uint32_t rv[4];
    #pragma unroll
    for (int j = 0; j < 4; ++j) {
        float o0 = f0 * bf2f(da[j] & 0xffff) + f1 * bf2f(db[j] & 0xffff);
        float o1 = f0 * bf2f(da[j] >> 16)    + f1 * bf2f(db[j] >> 16);
        rv[j] = (uint32_t)f2bf(o0) | ((uint32_t)f2bf(o1) << 16);
    }
    uint4 r; r.x = rv[0]; r.y = rv[1]; r.z = rv[2]; r.w = rv[3];
    ((uint4*)out)[i] = r;
}

// ---------------------------------------------------------------------------
extern "C" void kernel_launch(void* const* d_in, const int* in_sizes, int n_in,
                              void* d_out, int out_size, void* d_ws, size_t ws_size,
                              hipStream_t stream)
{
    (void)in_sizes; (void)n_in; (void)out_size; (void)ws_size;
    const float* x          = (const float*)d_in[0];
    const int*   seq_lens   = (const int*)  d_in[1];
    const int*   grid_sizes = (const int*)  d_in[2];
    const float* freqs      = (const float*)d_in[3];
    const float* Wq = (const float*)d_in[4];
    const float* bq = (const float*)d_in[5];
    const float* Wk = (const float*)d_in[6];
    const float* bk = (const float*)d_in[7];
    const float* Wv = (const float*)d_in[8];
    const float* bv = (const float*)d_in[9];
    const float* Wo = (const float*)d_in[10];
    const float* bo = (const float*)d_in[11];
    const float* gq = (const float*)d_in[12];
    const float* gk = (const float*)d_in[13];
    float* out = (float*)d_out;

    const int M = kB * kS;                       // 6144
    const size_t szX = (size_t)M * kDim;         // 9.44M elems
    const size_t szW = (size_t)kDim * kDim;

    ushort* xb   = (ushort*)d_ws;                // also reused as partial A
    ushort* wqb  = xb   + szX;                   // wq|wk|wv contiguous = fused B
    ushort* wkb  = wqb  + szW;
    ushort* wvb  = wkb  + szW;
    ushort* wob  = wvb  + szW;
    ushort* qkvb = wob  + szW;                   // [6144][4608]
    ushort* ab   = qkvb + 3*szX;
    ushort* vtb  = ab   + szX;
    ushort* pBuf = vtb  + szX;                   // partial B (bf16, szX)
    float*  biasqkv = (float*)(pBuf + szX);      // 4608 f32
    float*  ml   = biasqkv + kQKV;               // 2*12*2*3072*2 f32 = 294912

    dim3 blk(256);
    cvt_kernel<<<dim3((int)(szX/8/256)), blk, 0, stream>>>(x, xb, (int)(szX/8));
    cvt4_kernel<<<dim3((int)(szW/8/256), 4), blk, 0, stream>>>(
        Wq, Wk, Wv, Wo, wqb, wkb, wvb, wob, (int)(szW/8));
    biascat_kernel<<<dim3(18), blk, 0, stream>>>(bq, bk, bv, biasqkv);

    // fused QKV projection: N = 4608
    gemm_bf16<ushort><<<dim3(kQKV/128, M/128), blk, 0, stream>>>(
        xb, wqb, biasqkv, qkvb, M, kQKV, kDim);

    rmsrope_kernel<<<dim3(M, 2), dim3(192), 0, stream>>>(qkvb, gq, gk, freqs, grid_sizes);
    vtrans_kernel<<<dim3(kS/64, 2, kB*kHeads), blk, 0, stream>>>(qkvb, vtb);

    // split-K flash attention: 48 x 24 = 1152 blocks (xb reused as partial A)
    attn_kernel<<<dim3(48 * kHeads * kB), blk, 0, stream>>>(
        qkvb, vtb, xb, pBuf, ml, seq_lens);
    combine_kernel<<<dim3((int)(szX/8/256)), blk, 0, stream>>>(
        xb, pBuf, ml, ab, (int)(szX/8));

    gemm_bf16<float><<<dim3(kDim/128, M/128), blk, 0, stream>>>(
        ab, wob, bo, out, M, kDim, kDim);
}

// Round 10
// 421.841 us; speedup vs baseline: 1.0412x; 1.0412x over previous
//
#include <hip/hip_runtime.h>
#include <hip/hip_bf16.h>
#include <stdint.h>

typedef __attribute__((ext_vector_type(8))) short short8;
typedef __attribute__((ext_vector_type(4))) float f32x4;
typedef __attribute__((ext_vector_type(16))) float f32x16;

constexpr int kDim   = 1536;
constexpr int kHeads = 12;
constexpr int kHd    = 128;
constexpr int kS     = 3072;
constexpr int kB     = 2;
constexpr int kQKV   = 3 * kDim;               // 4608 fused row width
constexpr float kEps   = 1e-6f;
constexpr float kQMul  = 0.08838834764831845f * 1.44269504089f; // 1/sqrt(128)*log2(e)

__device__ __forceinline__ ushort f2bf(float f) {
    union { float f; uint32_t u; } c; c.f = f;
    uint32_t u = c.u;
    return (ushort)((u + 0x7fffu + ((u >> 16) & 1u)) >> 16);
}
__device__ __forceinline__ float bf2f(uint32_t h) {
    union { uint32_t u; float f; } c; c.u = h << 16;
    return c.f;
}
__device__ __forceinline__ void gload_lds16(const void* g, void* l) {
    __builtin_amdgcn_global_load_lds((const __attribute__((address_space(1))) void*)g,
                                     (__attribute__((address_space(3))) void*)l, 16, 0, 0);
}
__device__ __forceinline__ uint32_t cvtpk_bf16(float lo, float hi) {
    uint32_t r;
    asm("v_cvt_pk_bf16_f32 %0, %1, %2" : "=v"(r) : "v"(lo), "v"(hi));
    return r;
}

// ---------------------------------------------------------------------------
// fp32 -> bf16 convert, 8 elems/thread
// ---------------------------------------------------------------------------
__global__ __launch_bounds__(256)
void cvt_kernel(const float* __restrict__ in, ushort* __restrict__ out, int n8)
{
    int i = blockIdx.x * 256 + threadIdx.x;
    if (i >= n8) return;
    const float4* p = (const float4*)in + (size_t)i * 2;
    float4 a = p[0], b = p[1];
    uint4 r;
    r.x = (uint32_t)f2bf(a.x) | ((uint32_t)f2bf(a.y) << 16);
    r.y = (uint32_t)f2bf(a.z) | ((uint32_t)f2bf(a.w) << 16);
    r.z = (uint32_t)f2bf(b.x) | ((uint32_t)f2bf(b.y) << 16);
    r.w = (uint32_t)f2bf(b.z) | ((uint32_t)f2bf(b.w) << 16);
    ((uint4*)out)[i] = r;
}

// 4 weight tensors in one dispatch (blockIdx.y selects)
__global__ __launch_bounds__(256)
void cvt4_kernel(const float* __restrict__ s0, const float* __restrict__ s1,
                 const float* __restrict__ s2, const float* __restrict__ s3,
                 ushort* __restrict__ d0, ushort* __restrict__ d1,
                 ushort* __restrict__ d2, ushort* __restrict__ d3, int n8)
{
    int i = blockIdx.x * 256 + threadIdx.x;
    if (i >= n8) return;
    const float* in; ushort* out;
    switch (blockIdx.y) {
        case 0: in = s0; out = d0; break;
        case 1: in = s1; out = d1; break;
        case 2: in = s2; out = d2; break;
        default: in = s3; out = d3; break;
    }
    const float4* p = (const float4*)in + (size_t)i * 2;
    float4 a = p[0], b = p[1];
    uint4 r;
    r.x = (uint32_t)f2bf(a.x) | ((uint32_t)f2bf(a.y) << 16);
    r.y = (uint32_t)f2bf(a.z) | ((uint32_t)f2bf(a.w) << 16);
    r.z = (uint32_t)f2bf(b.x) | ((uint32_t)f2bf(b.y) << 16);
    r.w = (uint32_t)f2bf(b.z) | ((uint32_t)f2bf(b.w) << 16);
    ((uint4*)out)[i] = r;
}

// concat bq|bk|bv -> biasqkv[4608]
__global__ __launch_bounds__(256)
void biascat_kernel(const float* __restrict__ bq, const float* __restrict__ bk,
                    const float* __restrict__ bv, float* __restrict__ out)
{
    int i = blockIdx.x * 256 + threadIdx.x;
    if (i >= kQKV) return;
    float v = (i < kDim) ? bq[i] : (i < 2*kDim) ? bk[i - kDim] : bv[i - 2*kDim];
    out[i] = v;
}

// ---------------------------------------------------------------------------
// bf16 MFMA GEMM: C[M][N] = A[M][K] @ B[N][K]^T + bias   (m97-style 128^2, BK=32)
// (single-buffered: r9's 2-deep prefetch was null, reverted)
// ---------------------------------------------------------------------------
template<typename OutT>
__global__ __launch_bounds__(256)
void gemm_bf16(const ushort* __restrict__ A, const ushort* __restrict__ B,
               const float* __restrict__ bias, OutT* __restrict__ C,
               int M, int N, int K)
{
    __shared__ ushort As[128 * 32];
    __shared__ ushort Bs[128 * 32];
    const int t    = threadIdx.x;
    const int lane = t & 63;
    const int w    = t >> 6;
    const int wm = (w >> 1) * 64, wn = (w & 1) * 64;
    const int m0 = blockIdx.y * 128, n0 = blockIdx.x * 128;

    const int srow = t >> 2;
    const int skc  = (t & 3) * 8;
    const ushort* Ag = A + (size_t)(m0 + srow) * K + skc;
    const ushort* Bg = B + (size_t)(n0 + srow) * K + skc;
    const size_t half = (size_t)64 * K;

    f32x4 acc[4][4];
    #pragma unroll
    for (int m = 0; m < 4; ++m)
        #pragma unroll
        for (int n = 0; n < 4; ++n)
            #pragma unroll
            for (int i = 0; i < 4; ++i) acc[m][n][i] = 0.f;

    const int kk  = (lane >> 4) * 8;
    const int l15 = lane & 15;

    for (int k0 = 0; k0 < K; k0 += 32) {
        __syncthreads();
        gload_lds16(Ag + k0,        &As[t * 8]);
        gload_lds16(Ag + half + k0, &As[t * 8 + 2048]);
        gload_lds16(Bg + k0,        &Bs[t * 8]);
        gload_lds16(Bg + half + k0, &Bs[t * 8 + 2048]);
        __syncthreads();
        short8 af[4], bf[4];
        #pragma unroll
        for (int m = 0; m < 4; ++m) af[m] = *(const short8*)&As[(wm + m*16 + l15) * 32 + kk];
        #pragma unroll
        for (int n = 0; n < 4; ++n) bf[n] = *(const short8*)&Bs[(wn + n*16 + l15) * 32 + kk];
        #pragma unroll
        for (int m = 0; m < 4; ++m)
            #pragma unroll
            for (int n = 0; n < 4; ++n)
                acc[m][n] = __builtin_amdgcn_mfma_f32_16x16x32_bf16(af[m], bf[n], acc[m][n], 0, 0, 0);
    }

    const int r0 = (lane >> 4) * 4;
    #pragma unroll
    for (int m = 0; m < 4; ++m) {
        #pragma unroll
        for (int r = 0; r < 4; ++r) {
            const size_t row = (size_t)(m0 + wm + m*16 + r0 + r);
            #pragma unroll
            for (int n = 0; n < 4; ++n) {
                const int col = n0 + wn + n*16 + l15;
                float val = acc[m][n][r] + bias[col];
                if constexpr (sizeof(OutT) == 4) C[row * N + col] = val;
                else                             C[row * N + col] = f2bf(val);
            }
        }
    }
}

// ---------------------------------------------------------------------------
// V transpose from fused qkv: vt[b][h][d][s] = qkv[b][s][3072 + h*128 + d]
// ---------------------------------------------------------------------------
__global__ __launch_bounds__(256)
void vtrans_kernel(const ushort* __restrict__ qkv, ushort* __restrict__ vt)
{
    __shared__ ushort Ts[64][72];
    const int t  = threadIdx.x;
    const int s0 = blockIdx.x * 64;
    const int d0 = blockIdx.y * 64;
    const int bh = blockIdx.z;
    const int b = bh / kHeads, h = bh % kHeads;

    const int r = t >> 2, cc = (t & 3) * 16;
    const ushort* src = qkv + ((size_t)(b * kS) + s0 + r) * kQKV + 2*kDim + h * kHd + d0 + cc;
    uint4 a0 = *(const uint4*)src;
    uint4 a1 = *(const uint4*)(src + 8);
    *(uint4*)&Ts[r][cc]     = a0;
    *(uint4*)&Ts[r][cc + 8] = a1;
    __syncthreads();
    ushort tmp[16];
    #pragma unroll
    for (int j = 0; j < 16; ++j) tmp[j] = Ts[cc + j][r];
    ushort* dst = vt + ((size_t)(bh * kHd) + d0 + r) * kS + s0 + cc;
    *(uint4*)dst       = *(uint4*)&tmp[0];
    *(uint4*)(dst + 8) = *(uint4*)&tmp[8];
}

// ---------------------------------------------------------------------------
// RMSNorm + RoPE on q/k sections of fused qkv. 192 thr, 8 elems each.
// ---------------------------------------------------------------------------
__global__ __launch_bounds__(192)
void rmsrope_kernel(ushort* __restrict__ qkv,
                    const float* __restrict__ gq, const float* __restrict__ gk,
                    const float* __restrict__ freqs, const int* __restrict__ grid_sizes)
{
    __shared__ float red[4];
    const int row   = blockIdx.x;
    const int which = blockIdx.y;
    ushort* ptr = qkv + (size_t)row * kQKV + which * kDim;
    const float* g = which ? gk : gq;
    const float outmul = which ? 1.0f : kQMul;
    const int t = threadIdx.x;

    uint4 raw = ((const uint4*)ptr)[t];
    float v[8];
    v[0] = bf2f(raw.x & 0xffff); v[1] = bf2f(raw.x >> 16);
    v[2] = bf2f(raw.y & 0xffff); v[3] = bf2f(raw.y >> 16);
    v[4] = bf2f(raw.z & 0xffff); v[5] = bf2f(raw.z >> 16);
    v[6] = bf2f(raw.w & 0xffff); v[7] = bf2f(raw.w >> 16);

    float ss = 0.f;
    #pragma unroll
    for (int i = 0; i < 8; ++i) ss += v[i] * v[i];
    #pragma unroll
    for (int off = 32; off >= 1; off >>= 1) ss += __shfl_xor(ss, off);
    if ((t & 63) == 0) red[t >> 6] = ss;
    __syncthreads();
    const float scale = rsqrtf((red[0] + red[1] + red[2]) * (1.f / kDim) + kEps);

    const int b = row / kS, s = row % kS;
    const int gh = grid_sizes[b*3 + 1], gw = grid_sizes[b*3 + 2];
    const int hw  = gh * gw;
    const int fi  = s / hw;
    const int rem = s - fi * hw;
    const int hi  = rem / gw;
    const int wi  = rem - hi * gw;

    const float4 g0 = *(const float4*)(g + t*8);
    const float4 g1 = *(const float4*)(g + t*8 + 4);
    const float gv[8] = {g0.x, g0.y, g0.z, g0.w, g1.x, g1.y, g1.z, g1.w};

    uint32_t out[4];
    #pragma unroll
    for (int jj = 0; jj < 4; ++jj) {
        const int p = t*4 + jj;
        const int c = p & 63;
        const int pos = (c < 22) ? fi : (c < 43 ? hi : wi);
        const float ang = freqs[pos * 64 + c];
        float sn, cs;
        sincosf(ang, &sn, &cs);
        const float e0 = v[2*jj]   * scale * gv[2*jj];
        const float e1 = v[2*jj+1] * scale * gv[2*jj+1];
        const float o0 = (e0 * cs - e1 * sn) * outmul;
        const float o1 = (e0 * sn + e1 * cs) * outmul;
        out[jj] = (uint32_t)f2bf(o0) | ((uint32_t)f2bf(o1) << 16);
    }
    uint4 ov; ov.x = out[0]; ov.y = out[1]; ov.z = out[2]; ov.w = out[3];
    ((uint4*)ptr)[t] = ov;
}

// ---------------------------------------------------------------------------
// Flash attention, split-K (2 halves), swapped-QK^T 32x32x16 MFMA.
// Register-lean: the 64-key tile is processed as two sequential 32-key
// halves so only one f32x16 score block + one pack set is live at a time
// (~155 total regs incl. AGPR vs ~204 before) -> launch_bounds(256,3)
// gives 3 waves/SIMD (12 waves/CU) without spilling.
// ---------------------------------------------------------------------------
__global__ __launch_bounds__(256, 3)
void attn_kernel(const ushort* __restrict__ qkv, const ushort* __restrict__ vtb,
                 ushort* __restrict__ pA, ushort* __restrict__ pB,
                 float* __restrict__ ml, const int* __restrict__ seq_lens)
{
    __shared__ ushort Ks[64 * 128];
    __shared__ ushort VT[128 * 64];

    // bijective XCD remap: consecutive logical ids (sharing (h,b) K/V) land on
    // the same XCD's L2.  1152 % 8 == 0 -> L = (lin&7)*144 + (lin>>3).
    const int lin = blockIdx.x;
    const int L   = (lin & 7) * 144 + (lin >> 3);
    const int bh   = L / 48;
    const int rem  = L - bh * 48;
    const int half = rem / 24;
    const int qtile= rem - half * 24;
    const int h = bh % kHeads, b = bh / kHeads;
    const int seq = seq_lens[b];
    const int kbeg = half * (kS / 2);

    const int t = threadIdx.x, lane = t & 63, w = t >> 6;
    const int l31 = lane & 31, hi = lane >> 5;
    const int qrow = qtile * 128 + w * 32 + l31;

    const ushort* qbase = qkv + ((size_t)b * kS) * kQKV + h * kHd;
    const ushort* kbase = qkv + ((size_t)b * kS) * kQKV + kDim + h * kHd;
    const ushort* vtbase = vtb + ((size_t)(b * kHeads + h) * kHd) * kS;

    // Q fragments (B-operand): qf[kb][j] = Q[qrow][kb*16 + hi*8 + j]
    short8 qf[8];
    #pragma unroll
    for (int kb = 0; kb < 8; ++kb)
        qf[kb] = *(const short8*)(qbase + (size_t)qrow * kQKV + kb*16 + hi*8);

    f32x16 oacc[4];
    #pragma unroll
    for (int n = 0; n < 4; ++n)
        #pragma unroll
        for (int i = 0; i < 16; ++i) oacc[n][i] = 0.f;

    float m_run = -1e30f, l_run = 0.f;

    const int srow = t >> 4;                      // 0..15
    const int scol = (t & 15) * 8;
    const int kl   = scol ^ ((srow & 7) << 3);    // pre-swizzled K source col
    const int vd0  = t >> 3;                      // 0..31
    const int vscol = ((t & 7) * 8) ^ ((vd0 & 7) << 3);  // pre-swizzled V^T col

    for (int kt = 0; kt < kS/2; kt += 64) {
        const int k0 = kbeg + kt;
        __syncthreads();
        #pragma unroll
        for (int c = 0; c < 4; ++c) {
            gload_lds16(kbase + (size_t)(k0 + srow + c*16) * kQKV + kl, &Ks[t*8 + c*2048]);
            gload_lds16(vtbase + (size_t)(vd0 + c*32) * kS + k0 + vscol, &VT[t*8 + c*2048]);
        }
        __syncthreads();

        // ---- two sequential 32-key halves (register-lean) ----
        #pragma unroll
        for (int hb = 0; hb < 2; ++hb) {
            // S^T = K . Q^T for rows hb*32 + l31; reg r -> key (r&3)+8*(r>>2)+4*hi
            f32x16 s;
            #pragma unroll
            for (int i = 0; i < 16; ++i) s[i] = 0.f;
            __builtin_amdgcn_s_setprio(1);
            #pragma unroll
            for (int kb = 0; kb < 8; ++kb) {
                const int col = (kb*16 + hi*8) ^ ((l31 & 7) << 3);
                short8 kf = *(const short8*)&Ks[(hb*32 + l31) * 128 + col];
                s = __builtin_amdgcn_mfma_f32_32x32x16_bf16(kf, qf[kb], s, 0, 0, 0);
            }
            __builtin_amdgcn_s_setprio(0);

            // mask + half max (scores already in log2 domain via kQMul)
            const int kb0 = k0 + hb*32;
            float mx = -1e30f;
            if (kb0 + 32 > seq) {
                #pragma unroll
                for (int r = 0; r < 16; ++r) {
                    if (kb0 + (r&3) + 8*(r>>2) + 4*hi >= seq) s[r] = -1e30f;
                    mx = fmaxf(mx, s[r]);
                }
            } else {
                #pragma unroll
                for (int r = 0; r < 16; ++r) mx = fmaxf(mx, s[r]);
            }
            mx = fmaxf(mx, __shfl_xor(mx, 32));

            // defer-max online softmax (T13)
            const bool skip = (mx <= m_run + 11.0f);
            if (!__all(skip)) {
                const float mnew = fmaxf(m_run, mx);
                const float alpha = exp2f(m_run - mnew);
                m_run = mnew;
                l_run *= alpha;
                #pragma unroll
                for (int r = 0; r < 16; ++r) {
                    const float ar = __shfl(alpha, (r&3) + 8*(r>>2) + 4*hi);
                    #pragma unroll
                    for (int n = 0; n < 4; ++n) oacc[n][r] *= ar;
                }
            }

            float rs = 0.f;
            #pragma unroll
            for (int r = 0; r < 16; ++r) {
                s[r] = exp2f(s[r] - m_run);
                rs += s[r];
            }
            rs += __shfl_xor(rs, 32);
            l_run += rs;

            // pack P -> bf16 dwords (cvt_pk), exchange halves (shfl_xor)
            uint32_t u[8], wv[8];
            #pragma unroll
            for (int i = 0; i < 8; ++i) u[i] = cvtpk_bf16(s[2*i], s[2*i+1]);
            #pragma unroll
            for (int i = 0; i < 8; ++i) wv[i] = __shfl_xor(u[i], 32);
            union PF { uint32_t d[4]; short8 s8; };
            PF pa0, pa1;
            pa0.d[0] = hi ? wv[2] : u[0];  pa0.d[1] = hi ? wv[3] : u[1];
            pa0.d[2] = hi ? u[2] : wv[0];  pa0.d[3] = hi ? u[3] : wv[1];
            pa1.d[0] = hi ? wv[6] : u[4];  pa1.d[1] = hi ? wv[7] : u[5];
            pa1.d[2] = hi ? u[6] : wv[4];  pa1.d[3] = hi ? u[7] : wv[5];

            // PV for this half: k-slots hb*2 + {0,1}
            __builtin_amdgcn_s_setprio(1);
            #pragma unroll
            for (int kss = 0; kss < 2; ++kss) {
                const int ks = hb*2 + kss;
                #pragma unroll
                for (int n = 0; n < 4; ++n) {
                    const int d = n*32 + l31;
                    const int colv = (ks*16 + hi*8) ^ ((l31 & 7) << 3);
                    short8 vf = *(const short8*)&VT[d * 64 + colv];
                    oacc[n] = __builtin_amdgcn_mfma_f32_32x32x16_bf16(
                        (kss ? pa1 : pa0).s8, vf, oacc[n], 0, 0, 0);
                }
            }
            __builtin_amdgcn_s_setprio(0);
        }
    }

    // ---- epilogue: partial O' = O~/l (bf16) + per-row (m,l) ----
    ushort* pOut = half ? pB : pA;
    const float linv = 1.f / l_run;
    #pragma unroll
    for (int r = 0; r < 16; ++r) {
        const int qr = (r&3) + 8*(r>>2) + 4*hi;
        const float lr = __shfl(linv, qr);
        const size_t row = (size_t)(b * kS) + qtile * 128 + w * 32 + qr;
        #pragma unroll
        for (int n = 0; n < 4; ++n)
            pOut[row * kDim + h * kHd + n*32 + l31] = f2bf(oacc[n][r] * lr);
    }
    if (lane < 32) {
        const int s = qtile * 128 + w * 32 + l31;
        const size_t idx = ((((size_t)(b * kHeads + h)) * 2 + half) * kS + s) * 2;
        ml[idx]     = m_run;
        ml[idx + 1] = l_run;
    }
}

// ---------------------------------------------------------------------------
// Combine split-K partials: O = (a0*O'0 + a1*O'1)/(a0+a1), a_i = l_i*2^(m_i-m)
// ---------------------------------------------------------------------------
__global__ __launch_bounds__(256)
void combine_kernel(const ushort* __restrict__ pA, const ushort* __restrict__ pB,
                    const float* __restrict__ ml, ushort* __restrict__ out, int n8)
{
    int i = blockIdx.x * 256 + threadIdx.x;
    if (i >= n8) return;
    const int row = i / 192;               // 192 = kDim/8
    const int within = (i - row * 192) * 8;
    const int h = within >> 7;
    const int b = row / kS;
    const int s = row - b * kS;
    const size_t base = (((size_t)(b * kHeads + h)) * 2) * kS;
    const float m0 = ml[(base + s) * 2],        l0 = ml[(base + s) * 2 + 1];
    const float m1 = ml[(base + kS + s) * 2],   l1 = ml[(base + kS + s) * 2 + 1];
    const float m  = fmaxf(m0, m1);
    const float a0 = l0 * exp2f(m0 - m);
    const float a1 = l1 * exp2f(m1 - m);
    const float inv = 1.f / (a0 + a1);
    const float f0 = a0 * inv, f1 = a1 * inv;

    uint4 ua = ((const uint4*)pA)[i];
    uint4 ub = ((const uint4*)pB)[i];
    const uint32_t* da = (const uint32_t*)&ua;
    const uint32_t* db = (const uint32_t*)&ub;
    uint32_t rv[4];
    #pragma unroll
    for (int j = 0; j < 4; ++j) {
        float o0 = f0 * bf2f(da[j] & 0xffff) + f1 * bf2f(db[j] & 0xffff);
        float o1 = f0 * bf2f(da[j] >> 16)    + f1 * bf2f(db[j] >> 16);
        rv[j] = (uint32_t)f2bf(o0) | ((uint32_t)f2bf(o1) << 16);
    }
    uint4 r; r.x = rv[0]; r.y = rv[1]; r.z = rv[2]; r.w = rv[3];
    ((uint4*)out)[i] = r;
}

// ---------------------------------------------------------------------------
extern "C" void kernel_launch(void* const* d_in, const int* in_sizes, int n_in,
                              void* d_out, int out_size, void* d_ws, size_t ws_size,
                              hipStream_t stream)
{
    (void)in_sizes; (void)n_in; (void)out_size; (void)ws_size;
    const float* x          = (const float*)d_in[0];
    const int*   seq_lens   = (const int*)  d_in[1];
    const int*   grid_sizes = (const int*)  d_in[2];
    const float* freqs      = (const float*)d_in[3];
    const float* Wq = (const float*)d_in[4];
    const float* bq = (const float*)d_in[5];
    const float* Wk = (const float*)d_in[6];
    const float* bk = (const float*)d_in[7];
    const float* Wv = (const float*)d_in[8];
    const float* bv = (const float*)d_in[9];
    const float* Wo = (const float*)d_in[10];
    const float* bo = (const float*)d_in[11];
    const float* gq = (const float*)d_in[12];
    const float* gk = (const float*)d_in[13];
    float* out = (float*)d_out;

    const int M = kB * kS;                       // 6144
    const size_t szX = (size_t)M * kDim;         // 9.44M elems
    const size_t szW = (size_t)kDim * kDim;

    ushort* xb   = (ushort*)d_ws;                // also reused as partial A
    ushort* wqb  = xb   + szX;                   // wq|wk|wv contiguous = fused B
    ushort* wkb  = wqb  + szW;
    ushort* wvb  = wkb  + szW;
    ushort* wob  = wvb  + szW;
    ushort* qkvb = wob  + szW;                   // [6144][4608]
    ushort* ab   = qkvb + 3*szX;
    ushort* vtb  = ab   + szX;
    ushort* pBuf = vtb  + szX;                   // partial B (bf16, szX)
    float*  biasqkv = (float*)(pBuf + szX);      // 4608 f32
    float*  ml   = biasqkv + kQKV;               // 2*12*2*3072*2 f32 = 294912

    dim3 blk(256);
    cvt_kernel<<<dim3((int)(szX/8/256)), blk, 0, stream>>>(x, xb, (int)(szX/8));
    cvt4_kernel<<<dim3((int)(szW/8/256), 4), blk, 0, stream>>>(
        Wq, Wk, Wv, Wo, wqb, wkb, wvb, wob, (int)(szW/8));
    biascat_kernel<<<dim3(18), blk, 0, stream>>>(bq, bk, bv, biasqkv);

    // fused QKV projection: N = 4608
    gemm_bf16<ushort><<<dim3(kQKV/128, M/128), blk, 0, stream>>>(
        xb, wqb, biasqkv, qkvb, M, kQKV, kDim);

    rmsrope_kernel<<<dim3(M, 2), dim3(192), 0, stream>>>(qkvb, gq, gk, freqs, grid_sizes);
    vtrans_kernel<<<dim3(kS/64, 2, kB*kHeads), blk, 0, stream>>>(qkvb, vtb);

    // split-K flash attention: 48 x 24 = 1152 blocks (xb reused as partial A)
    attn_kernel<<<dim3(48 * kHeads * kB), blk, 0, stream>>>(
        qkvb, vtb, xb, pBuf, ml, seq_lens);
    combine_kernel<<<dim3((int)(szX/8/256)), blk, 0, stream>>>(
        xb, pBuf, ml, ab, (int)(szX/8));

    gemm_bf16<float><<<dim3(kDim/128, M/128), blk, 0, stream>>>(
        ab, wob, bo, out, M, kDim, kDim);
}